// Round 3
// baseline (329.826 us; speedup 1.0000x reference)
//
#include <hip/hip_runtime.h>
#include <hip/hip_bf16.h>
#include <cstdint>

#define BATCH   4096
#define IN_DIM  1024
#define OUT_DIM 1024
#define NEXP    16

typedef __bf16 bf16;
typedef __attribute__((ext_vector_type(8))) __bf16 bf16x8;
typedef __attribute__((ext_vector_type(4))) float  f32x4;

#define AS1 __attribute__((address_space(1)))
#define AS3 __attribute__((address_space(3)))

__device__ __forceinline__ void gld_lds16(const bf16* g, bf16* l) {
    __builtin_amdgcn_global_load_lds((const AS1 void*)g, (AS3 void*)l, 16, 0, 0);
}

// ---------------------------------------------------------------------------
// Fused pre-kernel.
// Blocks 0..511: x fp32 [4096][1024] -> 512 swizzled bf16 tiles (bblk, ks);
//   tile = 128 b-rows x 64 i = 16 KB; elem off = b_loc*64 + sc*8 holds
//   x[bblk*128+b_loc][ks*64 + (sc^(b_loc&7))*8 + j].
// Blocks 512..4607: W fp32 [16384][1024] -> fragment-ordered A-operand tiles
//   wt2, 8 KB per t2=(oblk<<8)|(ne<<4)|ks. Chunk c = sub*64+l, sub=kk*4+wm*2+mt,
//   holds W[ne*1024+ks*64+kk*32+lq*8+j][oblk*64+wm*32+mt*16+lr] at elem c*8+j.
//   Coalesced f32x4 reads + LDS transpose.
// ---------------------------------------------------------------------------
__global__ void pre_convert(const float* __restrict__ x, const float* __restrict__ W,
                            bf16* __restrict__ xt, bf16* __restrict__ wt2) {
    __shared__ float lt[64][68];
    int t = threadIdx.x;
    if (blockIdx.x < 512) {
        int tile = blockIdx.x;                 // (bblk<<4)|ks
        int bblk = tile >> 4, ks = tile & 15;
#pragma unroll
        for (int r = 0; r < 4; r++) {
            int q = r * 256 + t;
            int b_loc = q >> 3, sc = q & 7;
            int c = sc ^ (b_loc & 7);
            const float* src = x + (size_t)(bblk * 128 + b_loc) * IN_DIM + ks * 64 + c * 8;
            f32x4 a = *(const f32x4*)src;
            f32x4 b = *(const f32x4*)(src + 4);
            bf16x8 v;
#pragma unroll
            for (int j = 0; j < 4; j++) { v[j] = (bf16)a[j]; v[4 + j] = (bf16)b[j]; }
            *(bf16x8*)(xt + (size_t)tile * 8192 + q * 8) = v;
        }
    } else {
        int t2 = blockIdx.x - 512;             // (oblk<<8)|(ne<<4)|ks
        int oblk = t2 >> 8, ne = (t2 >> 4) & 15, ks = t2 & 15;
        int kbase = ne * 1024 + ks * 64, o0 = oblk * 64;
#pragma unroll
        for (int r = 0; r < 4; r++) {
            int q = r * 256 + t;               // 1024 f32x4 chunks
            int row = q >> 4, cg = q & 15;
            f32x4 v = *(const f32x4*)(W + (size_t)(kbase + row) * OUT_DIM + o0 + cg * 4);
#pragma unroll
            for (int c = 0; c < 4; c++) lt[row][cg * 4 + c] = v[c];
        }
        __syncthreads();
#pragma unroll
        for (int r = 0; r < 2; r++) {
            int c = r * 256 + t;               // 512 output chunks
            int sub = c >> 6, l = c & 63;
            int lr = l & 15, lq = l >> 4;
            int kk = sub >> 2, wm = (sub >> 1) & 1, mt = sub & 1;
            int o_loc = wm * 32 + mt * 16 + lr;
            int kb2 = kk * 32 + lq * 8;
            bf16x8 v;
#pragma unroll
            for (int j = 0; j < 8; j++) v[j] = (bf16)lt[kb2 + j][o_loc];
            *(bf16x8*)(wt2 + (size_t)t2 * 4096 + c * 8) = v;
        }
    }
}

// ---------------------------------------------------------------------------
// Transposed GEMM: D[o,b] = relu( Σ_ne cw[b,ne]·(Σ_i W[ne,i,o]·x[b,i]) + bias ).
// Block 64o x 128b, 4 waves (wm over o, wb over b), wave 32o x 64b.
// ks outer: x frags (B-operand) -> registers, reused over all 16 experts.
// ne inner: W frags (A-operand) loaded DIRECTLY global->reg from wt2
// (lane-linear, L1/L2-hot), scales per-lane scalars from cw. NO barriers,
// no LDS in the ne loop. One barrier per ks (double-buffered x staging).
// ---------------------------------------------------------------------------
__global__ __launch_bounds__(256, 3) void moe_gemm_t(
        const float* __restrict__ cw, const float* __restrict__ bias,
        const bf16* __restrict__ xt, const bf16* __restrict__ wt2,
        float* __restrict__ out) {
    int bblk = blockIdx.x;                 // 32
    int oblk = blockIdx.y;                 // 16 (consecutive blocks share oblk -> L2)
    int b0 = bblk * 128, o0 = oblk * 64;
    int t = threadIdx.x;
    int lane = t & 63, w = t >> 6;
    int wm = w & 1, wb = w >> 1;
    int lq = lane >> 4, lr = lane & 15;
    int swz = lr & 7;

    __shared__ bf16 As[2][128 * 64];       // 2 x 16 KB x-tile double buffer

    const f32x4 fz = {0.f, 0.f, 0.f, 0.f};
    f32x4 acc[2][4];                       // [mt(o)][bt(b)]
#pragma unroll
    for (int mt = 0; mt < 2; mt++)
#pragma unroll
        for (int bt = 0; bt < 4; bt++) acc[mt][bt] = fz;

    int brow[4];
#pragma unroll
    for (int bt = 0; bt < 4; bt++) brow[bt] = (wb * 64 + bt * 16 + lr) * 64;

    const bf16* xtile = xt + (size_t)(bblk * 16) * 8192;
    const bf16* wtile = wt2 + (size_t)(oblk * 256) * 4096;
    // per-lane cw row base (b = b0 + wb*64 + bt*16 + lr)
    const float* cwl = cw + (size_t)(b0 + wb * 64 + lr) * NEXP;

    // prefetch ks=0 x tile
#pragma unroll
    for (int r = 0; r < 4; r++)
        gld_lds16(xtile + r * 2048 + t * 8, &As[0][r * 2048 + t * 8]);

    for (int ks = 0; ks < 16; ks++) {
        __syncthreads();                   // As[ks&1] staged; As[ks+1&1] free
        if (ks < 15) {
            const bf16* nx = xtile + (size_t)(ks + 1) * 8192 + t * 8;
#pragma unroll
            for (int r = 0; r < 4; r++)
                gld_lds16(nx + r * 2048, &As[(ks + 1) & 1][r * 2048 + t * 8]);
        }
        // x fragments -> registers (B-operand: b=lr, i=lq*8+j)
        bf16x8 xf[2][4];
#pragma unroll
        for (int kk = 0; kk < 2; kk++)
#pragma unroll
            for (int bt = 0; bt < 4; bt++)
                xf[kk][bt] = *(const bf16x8*)
                    &As[ks & 1][brow[bt] + ((kk * 4 + lq) ^ swz) * 8];

        const bf16* wks = wtile + (size_t)ks * 4096;
#pragma unroll 2
        for (int g = 0; g < 4; g++) {
            f32x4 sc[4];                   // scales for experts g*4..g*4+3
#pragma unroll
            for (int bt = 0; bt < 4; bt++)
                sc[bt] = *(const f32x4*)(cwl + bt * 16 * NEXP + g * 4);
#pragma unroll
            for (int j2 = 0; j2 < 4; j2++) {
                int ne = g * 4 + j2;
                const bf16* wp = wks + (size_t)ne * (16 * 4096);
                bf16x8 wf[2][2];           // [kk][mt], A-operand, direct global
#pragma unroll
                for (int kk = 0; kk < 2; kk++)
#pragma unroll
                    for (int mt = 0; mt < 2; mt++)
                        wf[kk][mt] = *(const bf16x8*)
                            (wp + ((kk * 4 + wm * 2 + mt) * 64 + lane) * 8);
#pragma unroll
                for (int mt = 0; mt < 2; mt++)
#pragma unroll
                    for (int bt = 0; bt < 4; bt++) {
                        f32x4 p = __builtin_amdgcn_mfma_f32_16x16x32_bf16(
                            wf[0][mt], xf[0][bt], fz, 0, 0, 0);
                        p = __builtin_amdgcn_mfma_f32_16x16x32_bf16(
                            wf[1][mt], xf[1][bt], p, 0, 0, 0);
                        float s = sc[bt][j2];
                        acc[mt][bt] += s * p;          // v_pk_fma_f32 x2
                    }
            }
        }
    }

    // ---- bias as one MFMA k-step: A = bias^T frag, B = cw frag ----
    {
        bf16x8 bfrag[2];
#pragma unroll
        for (int mt = 0; mt < 2; mt++) {
            bf16x8 v;
#pragma unroll
            for (int j = 0; j < 8; j++) v[j] = (bf16)0.f;
            if (lq < 2) {                  // k = lq*8+j in 0..15 real
                int og = o0 + wm * 32 + mt * 16 + lr;
#pragma unroll
                for (int j = 0; j < 8; j++)
                    v[j] = (bf16)bias[(size_t)(lq * 8 + j) * OUT_DIM + og];
            }
            bfrag[mt] = v;
        }
        bf16x8 cwf[4];
#pragma unroll
        for (int bt = 0; bt < 4; bt++) {
            bf16x8 v;
#pragma unroll
            for (int j = 0; j < 8; j++) v[j] = (bf16)0.f;
            if (lq < 2) {
                const float* cr = cwl + bt * 16 * NEXP + lq * 8;
                f32x4 a = *(const f32x4*)cr;
                f32x4 b = *(const f32x4*)(cr + 4);
#pragma unroll
                for (int j = 0; j < 4; j++) { v[j] = (bf16)a[j]; v[4 + j] = (bf16)b[j]; }
            }
            cwf[bt] = v;
        }
#pragma unroll
        for (int mt = 0; mt < 2; mt++)
#pragma unroll
            for (int bt = 0; bt < 4; bt++)
                acc[mt][bt] = __builtin_amdgcn_mfma_f32_16x16x32_bf16(
                    bfrag[mt], cwf[bt], acc[mt][bt], 0, 0, 0);
    }

    // epilogue: D[o,b] -> out[b,o]; lane's f32x4 = 4 consecutive o at fixed b
#pragma unroll
    for (int mt = 0; mt < 2; mt++) {
        int og = o0 + wm * 32 + mt * 16 + lq * 4;
#pragma unroll
        for (int bt = 0; bt < 4; bt++) {
            int bg = b0 + wb * 64 + bt * 16 + lr;
            f32x4 v = acc[mt][bt];
#pragma unroll
            for (int r2 = 0; r2 < 4; r2++) v[r2] = v[r2] > 0.f ? v[r2] : 0.f;
            *(f32x4*)(out + (size_t)bg * OUT_DIM + og) = v;
        }
    }
}

// ---------------------------------------------------------------------------
// Insurance fallback if ws_size is too small.
// ---------------------------------------------------------------------------
__global__ void fallback_kernel(const float* __restrict__ x, const float* __restrict__ cw,
                                const float* __restrict__ W, const float* __restrict__ bias,
                                float* __restrict__ out) {
    int o = blockIdx.x * 256 + threadIdx.x;
    int b = o >> 10, oc = o & 1023;
    const float* xr = x + (size_t)b * IN_DIM;
    float accv = 0.f;
    for (int n = 0; n < NEXP; n++) {
        const float* wr = W + (size_t)n * IN_DIM * OUT_DIM + oc;
        float z = 0.f;
        for (int i = 0; i < IN_DIM; i++) z += xr[i] * wr[(size_t)i * OUT_DIM];
        accv += cw[(size_t)b * NEXP + n] * (z + bias[n * OUT_DIM + oc]);
    }
    out[o] = accv > 0.f ? accv : 0.f;
}

extern "C" void kernel_launch(void* const* d_in, const int* in_sizes, int n_in,
                              void* d_out, int out_size, void* d_ws, size_t ws_size,
                              hipStream_t stream) {
    const float* x    = (const float*)d_in[0];
    const float* cw   = (const float*)d_in[1];
    const float* W    = (const float*)d_in[2];
    const float* bias = (const float*)d_in[3];
    float* out = (float*)d_out;

    const size_t wt_elems = (size_t)NEXP * IN_DIM * OUT_DIM;   // 16.7M bf16
    const size_t xt_elems = (size_t)BATCH * IN_DIM;            // 4.2M bf16
    if (ws_size < (wt_elems + xt_elems) * sizeof(bf16)) {
        fallback_kernel<<<(BATCH * OUT_DIM) / 256, 256, 0, stream>>>(x, cw, W, bias, out);
        return;
    }
    bf16* wt2 = (bf16*)d_ws;
    bf16* xt = wt2 + wt_elems;

    pre_convert<<<4608, 256, 0, stream>>>(x, W, xt, wt2);
    moe_gemm_t<<<dim3(32, 16), 256, 0, stream>>>(cw, bias, xt, wt2, out);
}